// Round 8
// baseline (226.372 us; speedup 1.0000x reference)
//
#include <hip/hip_runtime.h>
#include <math.h>

// ---------------------------------------------------------------------------
// SpectralGroupAttention: prep(+conv/rmsnorm) -> MFMA-GEMM(inp|D) -> seqconv
// -> MFMA-GEMM(convlin) -> MFMA-GEMM(fc1|2|3, softplus, +bf16 B/C emit) ->
// merged scan (uniform-A SSD closed form w/ MFMA M = C.B^T, or sequential
// fallback) -> MFMA-GEMM(out_w) -> split-K FNN head.   9 dispatches.
// GEMMs use split-bf16 (hi+lo, 3 MFMA products) at BN=128 tiles.
// B=256, L=34, d=128, di=256, N=128, M=8704.
// ---------------------------------------------------------------------------

#define NB    256
#define LL    34
#define DD    128
#define DI    256
#define NN    128
#define MM    (NB*LL)       // 8704

using u16 = unsigned short;
typedef __attribute__((ext_vector_type(8))) short short8;
typedef __attribute__((ext_vector_type(4))) float f32x4;

__device__ __forceinline__ float silu_f(float x)  { return x / (1.f + __expf(-x)); }
__device__ __forceinline__ float softplus_f(float x) {
    return fmaxf(x, 0.f) + __logf(1.f + __expf(-fabsf(x)));
}
__device__ __forceinline__ float leaky_f(float x) { return (x >= 0.f) ? x : 0.01f * x; }

__device__ __forceinline__ u16 f2bf(float x) {            // RNE fp32->bf16
    unsigned u = __float_as_uint(x);
    return (u16)((u + 0x7FFF + ((u >> 16) & 1)) >> 16);
}
__device__ __forceinline__ float bf2f(u16 h) {
    return __uint_as_float(((unsigned)h) << 16);
}
__device__ __forceinline__ void f2pair(float v, u16* h, u16* l) {
    u16 hh = f2bf(v);
    *h = hh;
    *l = f2bf(v - bf2f(hh));
}

// ---------------------------------------------------------------------------
// prep_all: [0,1152) weight bf16 pairs + biases; [1152,1220) fnn1_w transpose;
// 1220 = A-uniformity check; [1221,5573) conv1d+leaky+rmsnorm (2 rows/block).
// ---------------------------------------------------------------------------
__global__ __launch_bounds__(256)
void prep_all_k(const float* __restrict__ inp_w, const float* __restrict__ D_w,
                const float* __restrict__ fc1_w, const float* __restrict__ fc2_w,
                const float* __restrict__ fc3_w, const float* __restrict__ convlin_w,
                const float* __restrict__ out_w,
                const float* __restrict__ inp_b, const float* __restrict__ D_b,
                const float* __restrict__ fc1_b, const float* __restrict__ fc2_b,
                const float* __restrict__ fc3_b,
                const float* __restrict__ W1, const float* __restrict__ A,
                const float* __restrict__ xin, const float* __restrict__ cw,
                const float* __restrict__ cb, const float* __restrict__ nw,
                u16* __restrict__ wc1h, u16* __restrict__ wc1l,
                u16* __restrict__ wc3h, u16* __restrict__ wc3l,
                u16* __restrict__ cvh,  u16* __restrict__ cvl,
                u16* __restrict__ owh,  u16* __restrict__ owl,
                float* __restrict__ bias1, float* __restrict__ bias3,
                float* __restrict__ W1T, int* __restrict__ flag,
                u16* __restrict__ XNh, u16* __restrict__ XNl)
{
    const int bx  = blockIdx.x;
    const int tid = threadIdx.x;
    __shared__ float tile[64][65];
    __shared__ float wsum[4];
    __shared__ int sflag;

    if (bx < 1152) {
        int i = bx * 256 + tid;
        if (i < 65536) {
            float v = (i < 32768) ? inp_w[i] : D_w[i - 32768];
            f2pair(v, &wc1h[i], &wc1l[i]);
        } else if (i < 196608) {
            int j = i - 65536;
            float v = (j < 65536) ? fc1_w[j] : (j < 98304 ? fc2_w[j - 65536] : fc3_w[j - 98304]);
            f2pair(v, &wc3h[j], &wc3l[j]);
        } else if (i < 262144) {
            int j = i - 196608;
            f2pair(convlin_w[j], &cvh[j], &cvl[j]);
        } else if (i < 294912) {
            int j = i - 262144;
            f2pair(out_w[j], &owh[j], &owl[j]);
        }
        if (i < 512)  bias1[i] = (i < 256) ? inp_b[i] : D_b[i - 256];
        else if (i < 1024) {
            int j = i - 512;
            bias3[j] = (j < 256) ? fc1_b[j] : (j < 384 ? fc2_b[j - 256] : fc3_b[j - 384]);
        }
    } else if (bx < 1220) {
        const int bt = bx - 1152;
        for (int p = 0; p < 16; p++) {
            int idx = tid + p * 256;
            int r = idx >> 6, c = idx & 63;
            tile[r][c] = W1[(size_t)r * 4352 + bt * 64 + c];
        }
        __syncthreads();
        for (int p = 0; p < 16; p++) {
            int idx = tid + p * 256;
            int cc = idx >> 6, rr = idx & 63;
            W1T[(size_t)(bt * 64 + cc) * 64 + rr] = tile[rr][cc];
        }
    } else if (bx == 1220) {
        if (tid == 0) sflag = 1;
        __syncthreads();
        bool ok = true;
        for (int k = 0; k < 128; k++) {
            int idx = tid + k * 256;
            ok &= (A[idx] == A[idx & ~127]);
        }
        if (!ok) sflag = 0;
        __syncthreads();
        if (tid == 0) *flag = sflag;
    } else {
        // conv1d(1->128,k=20,s=5)+leaky, RMSNorm over d=128; 2 rows per block
        const int half = tid >> 7;         // row within block
        const int c    = tid & 127;        // channel
        const int bl   = (bx - 1221) * 2 + half;
        const int b = bl / LL, l = bl % LL;
        const float* xr = xin + (size_t)b * 189 + l * 5;
        float g = cb[c];
        #pragma unroll
        for (int k = 0; k < 20; k++) g = fmaf(xr[k], cw[c * 20 + k], g);
        g = leaky_f(g);
        float s = g * g;
        #pragma unroll
        for (int m = 32; m >= 1; m >>= 1) s += __shfl_xor(s, m);
        if ((tid & 63) == 0) wsum[tid >> 6] = s;
        __syncthreads();
        float mean = (wsum[half * 2] + wsum[half * 2 + 1]) * (1.f / 128.f);
        float inv = 1.f / sqrtf(mean + 1e-5f);
        float v = g * inv * nw[c];
        f2pair(v, &XNh[(size_t)bl * DD + c], &XNl[(size_t)bl * DD + c]);
    }
}

// ---------------------------------------------------------------------------
// Split-bf16 MFMA GEMM.  Block 128 x BN, 4 waves (wm: 64-row half, wn:
// BN/2-col half), wave tile 64 x BN/2 of 16x16, K-step 32; 3 MFMA per pair.
// EPI: 0 fp32 out; 1 fp32+softplus cols<256; 2 bf16-pair out;
//      3 fp32+softplus cols<256 + bf16-pair B/C emit into BC strided rows
//        (row r base = BC + r*1024: [Bh 128|Bl 128|Ch 128|Cl 128] u16).
// ---------------------------------------------------------------------------
template <int K, int BN, int EPI>
__global__ __launch_bounds__(256)
void mgemm_k(const u16* __restrict__ Ah, const u16* __restrict__ Al,
             const u16* __restrict__ Wh, const u16* __restrict__ Wl,
             const float* __restrict__ bias,
             float* __restrict__ Y, int ldy,
             u16* __restrict__ Yh, u16* __restrict__ Yl,
             u16* __restrict__ BC)
{
    constexpr int JT = BN / 32;          // col 16-tiles per wave
    const int tid  = threadIdx.x;
    const int r0   = blockIdx.x * 128;
    const int c0   = blockIdx.y * BN;
    const int wave = tid >> 6;
    const int lane = tid & 63;
    const int wm   = wave & 1;
    const int wn   = wave >> 1;
    const int l15  = lane & 15;
    const int lq   = lane >> 4;

    __shared__ u16 sAh[128][40];
    __shared__ u16 sAl[128][40];
    __shared__ u16 sBh[BN][40];
    __shared__ u16 sBl[BN][40];

    f32x4 acc[4][JT];
    #pragma unroll
    for (int i = 0; i < 4; i++)
        #pragma unroll
        for (int j = 0; j < JT; j++) acc[i][j] = (f32x4){0.f, 0.f, 0.f, 0.f};

    const int a_row = tid >> 1;
    const int a_kb  = (tid & 1) * 16;
    const int b_row = (BN == 128) ? (tid >> 1) : (tid >> 2);
    const int b_ko  = (BN == 128) ? ((tid & 1) * 16) : ((tid & 3) * 8);

    for (int k0 = 0; k0 < K; k0 += 32) {
        const u16* ga = Ah + (size_t)(r0 + a_row) * K + k0 + a_kb;
        const u16* gl = Al + (size_t)(r0 + a_row) * K + k0 + a_kb;
        short8 vh0 = *(const short8*)(ga);
        short8 vh1 = *(const short8*)(ga + 8);
        short8 vl0 = *(const short8*)(gl);
        short8 vl1 = *(const short8*)(gl + 8);
        const u16* gb = Wh + (size_t)(c0 + b_row) * K + k0 + b_ko;
        const u16* gc = Wl + (size_t)(c0 + b_row) * K + k0 + b_ko;
        short8 wb0 = *(const short8*)(gb);
        short8 wc0 = *(const short8*)(gc);
        short8 wb1, wc1;
        if (BN == 128) {
            wb1 = *(const short8*)(gb + 8);
            wc1 = *(const short8*)(gc + 8);
        }

        *(short8*)&sAh[a_row][a_kb]     = vh0;
        *(short8*)&sAh[a_row][a_kb + 8] = vh1;
        *(short8*)&sAl[a_row][a_kb]     = vl0;
        *(short8*)&sAl[a_row][a_kb + 8] = vl1;
        *(short8*)&sBh[b_row][b_ko] = wb0;
        *(short8*)&sBl[b_row][b_ko] = wc0;
        if (BN == 128) {
            *(short8*)&sBh[b_row][b_ko + 8] = wb1;
            *(short8*)&sBl[b_row][b_ko + 8] = wc1;
        }
        __syncthreads();

        short8 fah[4], fal[4], fbh[JT], fbl[JT];
        #pragma unroll
        for (int i = 0; i < 4; i++) {
            fah[i] = *(const short8*)&sAh[wm * 64 + i * 16 + l15][lq * 8];
            fal[i] = *(const short8*)&sAl[wm * 64 + i * 16 + l15][lq * 8];
        }
        #pragma unroll
        for (int j = 0; j < JT; j++) {
            fbh[j] = *(const short8*)&sBh[wn * (BN / 2) + j * 16 + l15][lq * 8];
            fbl[j] = *(const short8*)&sBl[wn * (BN / 2) + j * 16 + l15][lq * 8];
        }
        #pragma unroll
        for (int i = 0; i < 4; i++)
            #pragma unroll
            for (int j = 0; j < JT; j++) {
                acc[i][j] = __builtin_amdgcn_mfma_f32_16x16x32_bf16(fah[i], fbh[j], acc[i][j], 0, 0, 0);
                acc[i][j] = __builtin_amdgcn_mfma_f32_16x16x32_bf16(fah[i], fbl[j], acc[i][j], 0, 0, 0);
                acc[i][j] = __builtin_amdgcn_mfma_f32_16x16x32_bf16(fal[i], fbh[j], acc[i][j], 0, 0, 0);
            }
        __syncthreads();
    }

    #pragma unroll
    for (int i = 0; i < 4; i++) {
        int gr = r0 + wm * 64 + i * 16 + lq * 4;
        #pragma unroll
        for (int j = 0; j < JT; j++) {
            int gc = c0 + wn * (BN / 2) + j * 16 + l15;
            float bb = bias[gc];
            #pragma unroll
            for (int r = 0; r < 4; r++) {
                float v = acc[i][j][r] + bb;
                if (EPI == 1 || EPI == 3) { if (gc < 256) v = softplus_f(v); }
                if (EPI == 2) {
                    u16 hh, ll;
                    f2pair(v, &hh, &ll);
                    Yh[(size_t)(gr + r) * ldy + gc] = hh;
                    Yl[(size_t)(gr + r) * ldy + gc] = ll;
                } else {
                    Y[(size_t)(gr + r) * ldy + gc] = v;
                    if (EPI == 3 && gc >= 256) {
                        u16 hh, ll;
                        f2pair(v, &hh, &ll);
                        u16* rb = BC + (size_t)(gr + r) * 1024
                                     + ((gc < 384) ? 0 : 256) + (gc & 127);
                        rb[0]   = hh;
                        rb[128] = ll;
                    }
                }
            }
        }
    }
}

// ---------------------------------------------------------------------------
// seqconv: Conv1d over L as channels + bias + silu; emits bf16 hi/lo pair.
// ---------------------------------------------------------------------------
__global__ __launch_bounds__(256)
void seqconv_k(const float* __restrict__ XP, int ldxp,
               const float* __restrict__ w, const float* __restrict__ bias,
               u16* __restrict__ XCh, u16* __restrict__ XCl)
{
    const int b   = blockIdx.x;
    const int tid = threadIdx.x;
    const int tx  = tid & 63;
    const int ty  = tid >> 6;
    const int j0  = tx * 4;

    __shared__ float sx[LL][264];
    __shared__ float sw[LL][112];

    for (int idx = tid; idx < LL * 256; idx += 256) {
        int li = idx >> 8, jj = idx & 255;
        sx[li][jj + 1] = XP[(size_t)(b * LL + li) * ldxp + jj];
    }
    if (tid < LL) { sx[tid][0] = 0.f; sx[tid][257] = 0.f; }
    for (int idx = tid; idx < LL * LL * 3; idx += 256) {
        int lo = idx / 102;
        int rem = idx - lo * 102;
        int li = rem / 3;
        int k  = rem - li * 3;
        sw[li][lo * 3 + k] = w[idx];
    }
    __syncthreads();

    const int base = ty * 9 - (ty == 3 ? 1 : 0);
    const int cnt  = (ty < 2) ? 9 : 8;

    float acc[9][4];
    #pragma unroll
    for (int i = 0; i < 9; i++)
        #pragma unroll
        for (int jj = 0; jj < 4; jj++) acc[i][jj] = 0.f;

    for (int li = 0; li < LL; li++) {
        float4 xa = *(const float4*)&sx[li][j0];
        float2 xb = *(const float2*)&sx[li][j0 + 4];
        float xv[6] = {xa.x, xa.y, xa.z, xa.w, xb.x, xb.y};
        const float* swr = &sw[li][0];
        #pragma unroll
        for (int i = 0; i < 9; i++) {
            if (i < cnt) {
                int lo3 = (base + i) * 3;
                float w0 = swr[lo3 + 0];
                float w1 = swr[lo3 + 1];
                float w2 = swr[lo3 + 2];
                #pragma unroll
                for (int jj = 0; jj < 4; jj++) {
                    acc[i][jj] = fmaf(w0, xv[jj],     acc[i][jj]);
                    acc[i][jj] = fmaf(w1, xv[jj + 1], acc[i][jj]);
                    acc[i][jj] = fmaf(w2, xv[jj + 2], acc[i][jj]);
                }
            }
        }
    }

    #pragma unroll
    for (int i = 0; i < 9; i++) {
        if (i < cnt) {
            int lo = base + i;
            float bb = bias[lo];
            ushort4 oh, ol;
            float v0 = silu_f(acc[i][0] + bb);
            float v1 = silu_f(acc[i][1] + bb);
            float v2 = silu_f(acc[i][2] + bb);
            float v3 = silu_f(acc[i][3] + bb);
            f2pair(v0, &oh.x, &ol.x);
            f2pair(v1, &oh.y, &ol.y);
            f2pair(v2, &oh.z, &ol.z);
            f2pair(v3, &oh.w, &ol.w);
            size_t o = (size_t)(b * LL + lo) * DI + j0;
            *(ushort4*)&XCh[o] = oh;
            *(ushort4*)&XCl[o] = ol;
        }
    }
}

// ---------------------------------------------------------------------------
// ssd_tail<Q>: triangular contraction for l = Q, Q+4, ... (static unroll so
// u[]/eS[] stay in registers), + fused silu gate, bf16-pair store.
// ---------------------------------------------------------------------------
template <int Q>
__device__ __forceinline__ void ssd_tail(const float (*Msh)[49],
                                         const float (&u)[LL], const float (&eS)[LL],
                                         const float* __restrict__ pG,
                                         u16* __restrict__ pGh, u16* __restrict__ pGl)
{
    #pragma unroll
    for (int l = Q; l < LL; l += 4) {
        float acc = 0.f;
        #pragma unroll
        for (int t = 0; t <= l; t++) acc = fmaf(Msh[l][t], u[t], acc);
        float xs = eS[l] * acc;
        float g = silu_f(xs) * silu_f(pG[l * 512]);
        u16 hh, ll2;
        f2pair(g, &hh, &ll2);
        pGh[l * 256] = hh;
        pGl[l * 256] = ll2;
    }
}

// ---------------------------------------------------------------------------
// Merged scan, grid (4, NB).  Uniform-A path (flag=1): SSD closed form —
// M = C.B^T via MFMA on bf16 pairs; block handles d in [bx*64, bx*64+64),
// thread = (d = bx*64 + lane&63, quarter q = tid>>6); quarters split output
// l's (l = q mod 4).  General-A path (flag=0): sequential recurrence,
// d0 = bx*64, identical to round-5 fallback.
// ---------------------------------------------------------------------------
__global__ __launch_bounds__(256)
void scan_k(const int* __restrict__ flag,
            const float* __restrict__ dBC,   // [8704,512] delta|B|C fp32
            const u16* __restrict__ BC,      // strided bf16 pairs, row*1024
            const u16* __restrict__ Xh, const u16* __restrict__ Xl,
            const float* __restrict__ A,
            const float* __restrict__ DG,    // buf1, dgate at cols 256+
            u16* __restrict__ Gh, u16* __restrict__ Gl)
{
    const int bx  = blockIdx.x;
    const int b   = blockIdx.y;
    const int tid = threadIdx.x;

    __shared__ u16 sBh[48][136], sBl[48][136];
    __shared__ u16 sCh[48][136], sCl[48][136];
    __shared__ float sM[48][49];

    if (*flag != 0) {
        const int wave = tid >> 6;
        const int lane = tid & 63;
        const int l15  = lane & 15;
        const int lq   = lane >> 4;

        // ---- stage bf16 B/C pairs ----
        const u16* base = BC + (size_t)b * LL * 1024;
        for (int idx = tid; idx < LL * 16; idx += 256) {
            int l = idx >> 4, c = (idx & 15) << 3;
            const u16* row = base + l * 1024;
            *(short8*)&sBh[l][c] = *(const short8*)&row[c];
            *(short8*)&sBl[l][c] = *(const short8*)&row[128 + c];
            *(short8*)&sCh[l][c] = *(const short8*)&row[256 + c];
            *(short8*)&sCl[l][c] = *(const short8*)&row[384 + c];
        }
        __syncthreads();

        // ---- M = C.B^T via MFMA (3x3 16-tiles, K=128 in 4 steps) ----
        for (int tt = wave; tt < 9; tt += 4) {
            int ti = tt / 3, tj = tt - ti * 3;
            f32x4 acc = (f32x4){0.f, 0.f, 0.f, 0.f};
            #pragma unroll
            for (int ks = 0; ks < 4; ks++) {
                short8 ch = *(const short8*)&sCh[ti * 16 + l15][ks * 32 + lq * 8];
                short8 cl = *(const short8*)&sCl[ti * 16 + l15][ks * 32 + lq * 8];
                short8 bh = *(const short8*)&sBh[tj * 16 + l15][ks * 32 + lq * 8];
                short8 bl = *(const short8*)&sBl[tj * 16 + l15][ks * 32 + lq * 8];
                acc = __builtin_amdgcn_mfma_f32_16x16x32_bf16(ch, bh, acc, 0, 0, 0);
                acc = __builtin_amdgcn_mfma_f32_16x16x32_bf16(ch, bl, acc, 0, 0, 0);
                acc = __builtin_amdgcn_mfma_f32_16x16x32_bf16(cl, bh, acc, 0, 0, 0);
            }
            #pragma unroll
            for (int r = 0; r < 4; r++)
                sM[ti * 16 + lq * 4 + r][tj * 16 + l15] = acc[r];
        }
        __syncthreads();

        // ---- per-d cumsum + u (quarters redundant), split-l tail ----
        const int d = (bx << 6) + lane;
        const int q = wave;
        const float a_d = A[(size_t)d * NN];
        const float* pDel = dBC + (size_t)b * LL * 512 + d;
        const u16* pXh = Xh + (size_t)b * LL * 256 + d;
        const u16* pXl = Xl + (size_t)b * LL * 256 + d;

        float u[LL], eS[LL];
        float S = 0.f;
        #pragma unroll
        for (int l = 0; l < LL; l++) {
            float dl = pDel[l * 512];
            S = fmaf(dl, a_d, S);
            eS[l] = __expf(S);
            float xv = bf2f(pXh[l * 256]) + bf2f(pXl[l * 256]);
            u[l] = __expf(-S) * dl * xv;
        }

        const float* pG = DG + (size_t)b * LL * 512 + 256 + d;
        u16* pGh = Gh + (size_t)b * LL * 256 + d;
        u16* pGl = Gl + (size_t)b * LL * 256 + d;
        switch (q) {
            case 0: ssd_tail<0>(sM, u, eS, pG, pGh, pGl); break;
            case 1: ssd_tail<1>(sM, u, eS, pG, pGh, pGl); break;
            case 2: ssd_tail<2>(sM, u, eS, pG, pGh, pGl); break;
            default: ssd_tail<3>(sM, u, eS, pG, pGh, pGl); break;
        }
        return;
    }

    // ---------------- general-A sequential fallback ----------------
    const int d0 = bx * 64;
    const int sub = tid & 15;
    const int pg  = tid >> 4;
    const int dbase = d0 + pg * 4;
    const int nA = sub * 4;

    float a[4][8], h[4][8];
    #pragma unroll
    for (int dd = 0; dd < 4; dd++) {
        const float* Ar = A + (size_t)(dbase + dd) * NN;
        float4 q0 = *(const float4*)(Ar + nA);
        float4 q1 = *(const float4*)(Ar + 64 + nA);
        a[dd][0]=q0.x; a[dd][1]=q0.y; a[dd][2]=q0.z; a[dd][3]=q0.w;
        a[dd][4]=q1.x; a[dd][5]=q1.y; a[dd][6]=q1.z; a[dd][7]=q1.w;
        #pragma unroll
        for (int j = 0; j < 8; j++) h[dd][j] = 0.f;
    }

    const float* pD  = dBC + (size_t)b * LL * 512 + dbase;
    const float* pBC = dBC + (size_t)b * LL * 512 + 256 + nA;
    const u16*  pXh = Xh  + (size_t)b * LL * 256 + dbase;
    const u16*  pXl = Xl  + (size_t)b * LL * 256 + dbase;
    const float* pG  = DG  + (size_t)b * LL * 512 + 256 + dbase;
    u16* pGh = Gh + (size_t)b * LL * 256 + dbase;
    u16* pGl = Gl + (size_t)b * LL * 256 + dbase;

    for (int l = 0; l < LL; l++) {
        float4  cD  = *(const float4*)(pD);
        ushort4 cXh = *(const ushort4*)(pXh);
        ushort4 cXl = *(const ushort4*)(pXl);
        float4 cB0 = *(const float4*)(pBC);
        float4 cB1 = *(const float4*)(pBC + 64);
        float4 cC0 = *(const float4*)(pBC + 128);
        float4 cC1 = *(const float4*)(pBC + 192);
        pD += 512; pBC += 512; pXh += 256; pXl += 256;

        float xv[4] = { bf2f(cXh.x) + bf2f(cXl.x), bf2f(cXh.y) + bf2f(cXl.y),
                        bf2f(cXh.z) + bf2f(cXl.z), bf2f(cXh.w) + bf2f(cXl.w) };
        float dl[4] = {cD.x, cD.y, cD.z, cD.w};
        float dx[4] = {cD.x * xv[0], cD.y * xv[1], cD.z * xv[2], cD.w * xv[3]};
        float bv[8] = {cB0.x,cB0.y,cB0.z,cB0.w,cB1.x,cB1.y,cB1.z,cB1.w};
        float cv[8] = {cC0.x,cC0.y,cC0.z,cC0.w,cC1.x,cC1.y,cC1.z,cC1.w};

        float accd[4] = {0.f, 0.f, 0.f, 0.f};
        #pragma unroll
        for (int dd = 0; dd < 4; dd++)
            #pragma unroll
            for (int j = 0; j < 8; j++) {
                float dA = __expf(dl[dd] * a[dd][j]);
                h[dd][j] = fmaf(dA, h[dd][j], dx[dd] * bv[j]);
                accd[dd] = fmaf(cv[j], h[dd][j], accd[dd]);
            }
        #pragma unroll
        for (int dd = 0; dd < 4; dd++) {
            float v = accd[dd];
            v += __shfl_xor(v, 1);
            v += __shfl_xor(v, 2);
            v += __shfl_xor(v, 4);
            v += __shfl_xor(v, 8);
            accd[dd] = v;
        }
        if (sub == 0) {
            float4 dg = *(const float4*)(pG);
            ushort4 oh, ol;
            float g0 = silu_f(accd[0]) * silu_f(dg.x);
            float g1 = silu_f(accd[1]) * silu_f(dg.y);
            float g2 = silu_f(accd[2]) * silu_f(dg.z);
            float g3 = silu_f(accd[3]) * silu_f(dg.w);
            f2pair(g0, &oh.x, &ol.x);
            f2pair(g1, &oh.y, &ol.y);
            f2pair(g2, &oh.z, &ol.z);
            f2pair(g3, &oh.w, &ol.w);
            *(ushort4*)pGh = oh;
            *(ushort4*)pGl = ol;
        }
        pG += 512; pGh += 256; pGl += 256;
    }
}

// ---------------------------------------------------------------------------
// FNN stage 1: split-K partials (deterministic).
// ---------------------------------------------------------------------------
__global__ __launch_bounds__(256)
void fnn1_k(const float* __restrict__ F, const float* __restrict__ W1T,
            float* __restrict__ partials)
{
    const int btile = blockIdx.x;
    const int kc    = blockIdx.y;
    const int tid   = threadIdx.x;
    __shared__ float sf[16][260];
    for (int i = tid; i < 16 * 256; i += 256) {
        int r = i >> 8, c = i & 255;
        sf[r][c] = F[(size_t)(btile * 16 + r) * 4352 + kc * 256 + c];
    }
    __syncthreads();

    const int o  = tid & 63;
    const int bq = tid >> 6;
    const float* w = W1T + (size_t)(kc * 256) * 64 + o;
    float acc[4] = {0.f, 0.f, 0.f, 0.f};
    for (int k = 0; k < 256; k += 4) {
        float w0 = w[(size_t)(k + 0) * 64];
        float w1 = w[(size_t)(k + 1) * 64];
        float w2 = w[(size_t)(k + 2) * 64];
        float w3 = w[(size_t)(k + 3) * 64];
        #pragma unroll
        for (int bj = 0; bj < 4; bj++) {
            float4 f4 = *(const float4*)&sf[bq * 4 + bj][k];
            acc[bj] = fmaf(w0, f4.x, acc[bj]);
            acc[bj] = fmaf(w1, f4.y, acc[bj]);
            acc[bj] = fmaf(w2, f4.z, acc[bj]);
            acc[bj] = fmaf(w3, f4.w, acc[bj]);
        }
    }
    #pragma unroll
    for (int bj = 0; bj < 4; bj++)
        partials[(size_t)kc * 16384 + (btile * 16 + bq * 4 + bj) * 64 + o] = acc[bj];
}

// ---------------------------------------------------------------------------
// FNN stage 2: reduce partials, leaky, then @fnn2_w.T + b2 -> out[b][32].
// ---------------------------------------------------------------------------
__global__ __launch_bounds__(64)
void fnn2_k(const float* __restrict__ partials,
            const float* __restrict__ B1,
            const float* __restrict__ W2, const float* __restrict__ B2,
            float* __restrict__ out)
{
    int b = blockIdx.x;
    int t = threadIdx.x;
    __shared__ float s1[64];
    float acc = B1[t];
    #pragma unroll
    for (int kc = 0; kc < 17; kc++)
        acc += partials[(size_t)kc * 16384 + b * 64 + t];
    s1[t] = leaky_f(acc);
    __syncthreads();

    if (t < 32) {
        float acc2 = B2[t];
        const float* w2 = W2 + t * 64;
        #pragma unroll
        for (int j = 0; j < 64; j++) acc2 = fmaf(s1[j], w2[j], acc2);
        out[(size_t)b * 32 + t] = acc2;
    }
}

// ---------------------------------------------------------------------------
extern "C" void kernel_launch(void* const* d_in, const int* in_sizes, int n_in,
                              void* d_out, int out_size, void* d_ws, size_t ws_size,
                              hipStream_t stream)
{
    const float* x        = (const float*)d_in[0];
    const float* conv_w   = (const float*)d_in[1];
    const float* conv_b   = (const float*)d_in[2];
    const float* norm_w   = (const float*)d_in[3];
    const float* inp_w    = (const float*)d_in[4];
    const float* inp_b    = (const float*)d_in[5];
    const float* seqconv_w= (const float*)d_in[6];
    const float* seqconv_b= (const float*)d_in[7];
    const float* convlin_w= (const float*)d_in[8];
    const float* convlin_b= (const float*)d_in[9];
    const float* fc1_w    = (const float*)d_in[10];
    const float* fc1_b    = (const float*)d_in[11];
    const float* fc2_w    = (const float*)d_in[12];
    const float* fc2_b    = (const float*)d_in[13];
    const float* fc3_w    = (const float*)d_in[14];
    const float* fc3_b    = (const float*)d_in[15];
    const float* A        = (const float*)d_in[16];
    const float* D_w      = (const float*)d_in[17];
    const float* D_b      = (const float*)d_in[18];
    const float* out_w    = (const float*)d_in[19];
    const float* out_b    = (const float*)d_in[20];
    const float* fnn1_w   = (const float*)d_in[21];
    const float* fnn1_b   = (const float*)d_in[22];
    const float* fnn2_w   = (const float*)d_in[23];
    const float* fnn2_b   = (const float*)d_in[24];

    // ---- workspace layout (bytes) ----
    char* W = (char*)d_ws;
    float* buf1  = (float*)(W + 0);           // [8704,512] fp32  xp|dgate;
                                              // xp half reused for bf16 B/C pairs
    float* buf3  = (float*)(W + 17825792);    // [8704,512] fp32  delta|B|C ; partials later
    u16*   xnh   = (u16*)  (W + 35651584);    // [8704,128]
    u16*   xnl   = (u16*)  (W + 37879808);
    u16*   xc2h  = (u16*)  (W + 35651584);    // [8704,256] (xn dead)
    float* fout  = (float*)(W + 35651584);    // [8704,128] fp32 (later)
    u16*   xc2l  = (u16*)  (W + 40108032);    // [8704,256]
    u16*   xch   = (u16*)  (W + 44564480);    // [8704,256] ; gateh later
    u16*   xcl   = (u16*)  (W + 49020928);    // [8704,256] ; gatel later
    float* w1t   = (float*)(W + 53477376);    // [4352,64]
    u16*   wc1h  = (u16*)  (W + 54591488);
    u16*   wc1l  = (u16*)  (W + 54722560);
    u16*   wc3h  = (u16*)  (W + 54853632);
    u16*   wc3l  = (u16*)  (W + 55115776);
    u16*   cvh   = (u16*)  (W + 55377920);
    u16*   cvl   = (u16*)  (W + 55508992);
    u16*   owh   = (u16*)  (W + 55640064);
    u16*   owl   = (u16*)  (W + 55705600);
    float* bias1 = (float*)(W + 55771136);
    float* bias3 = (float*)(W + 55773184);
    int*   uflag = (int*)  (W + 55775232);
    u16* gateh = xch;
    u16* gatel = xcl;
    u16* bcpair = (u16*)buf1;                 // xp half of buf1 (dead after seqconv)
    float* partials = buf3;

    // prep (weights, transpose, A-check) + conv/rmsnorm fused
    prep_all_k<<<5573, 256, 0, stream>>>(inp_w, D_w, fc1_w, fc2_w, fc3_w,
                                         convlin_w, out_w,
                                         inp_b, D_b, fc1_b, fc2_b, fc3_b,
                                         fnn1_w, A, x, conv_w, conv_b, norm_w,
                                         wc1h, wc1l, wc3h, wc3l, cvh, cvl,
                                         owh, owl, bias1, bias3, w1t, uflag,
                                         xnh, xnl);

    // buf1 = xn @ [inp_w;D_w].T + [inp_b|D_b]          (fp32 out)
    mgemm_k<128, 128, 0><<<dim3(MM / 128, 4), 256, 0, stream>>>(
        xnh, xnl, wc1h, wc1l, bias1, buf1, 512, nullptr, nullptr, nullptr);

    seqconv_k<<<NB, 256, 0, stream>>>(buf1, 512, seqconv_w, seqconv_b, xch, xcl);

    // xc2 = xc @ convlin_w.T + convlin_b               (bf16-pair out)
    mgemm_k<256, 128, 2><<<dim3(MM / 128, 2), 256, 0, stream>>>(
        xch, xcl, cvh, cvl, convlin_b, nullptr, 256, xc2h, xc2l, nullptr);

    // buf3 = xc2 @ [fc1;fc2;fc3].T + bias3, softplus on delta cols,
    // B/C also emitted as bf16 pairs into buf1's xp half
    mgemm_k<256, 128, 3><<<dim3(MM / 128, 4), 256, 0, stream>>>(
        xc2h, xc2l, wc3h, wc3l, bias3, buf3, 512, nullptr, nullptr, bcpair);

    // merged scan: SSD (uniform A, MFMA M) or sequential fallback
    scan_k<<<dim3(4, NB), 256, 0, stream>>>(uflag, buf3, bcpair, xc2h, xc2l,
                                            A, buf1, gateh, gatel);

    // fout = gate @ out_w.T + out_b                    (fp32 out)
    mgemm_k<256, 64, 0><<<dim3(MM / 128, 2), 256, 0, stream>>>(
        gateh, gatel, owh, owl, out_b, fout, 128, nullptr, nullptr, nullptr);

    fnn1_k<<<dim3(16, 17), 256, 0, stream>>>(fout, w1t, partials);
    fnn2_k<<<NB, 64, 0, stream>>>(partials, fnn1_b, fnn2_w, fnn2_b,
                                  (float*)d_out);
}

// Round 9
// 221.645 us; speedup vs baseline: 1.0213x; 1.0213x over previous
//
#include <hip/hip_runtime.h>
#include <math.h>

// ---------------------------------------------------------------------------
// SpectralGroupAttention: prep(+conv/rmsnorm) -> MFMA-GEMM(inp|D) -> seqconv
// -> MFMA-GEMM(convlin) -> MFMA-GEMM(fc1|2|3, softplus, +bf16 B/C emit) ->
// merged scan (uniform-A SSD closed form w/ MFMA M = C.B^T, or sequential
// fallback) -> MFMA-GEMM(out_w) -> split-K FNN head.   9 dispatches.
// GEMMs use split-bf16 (hi+lo, 3 MFMA products) at BN=64 tiles (BN=128
// regressed: 136-272 blocks -> <=1 block/CU, idle CUs + straggler wave).
// B=256, L=34, d=128, di=256, N=128, M=8704.
// ---------------------------------------------------------------------------

#define NB    256
#define LL    34
#define DD    128
#define DI    256
#define NN    128
#define MM    (NB*LL)       // 8704

using u16 = unsigned short;
typedef __attribute__((ext_vector_type(8))) short short8;
typedef __attribute__((ext_vector_type(4))) float f32x4;

__device__ __forceinline__ float silu_f(float x)  { return x / (1.f + __expf(-x)); }
__device__ __forceinline__ float softplus_f(float x) {
    return fmaxf(x, 0.f) + __logf(1.f + __expf(-fabsf(x)));
}
__device__ __forceinline__ float leaky_f(float x) { return (x >= 0.f) ? x : 0.01f * x; }

__device__ __forceinline__ u16 f2bf(float x) {            // RNE fp32->bf16
    unsigned u = __float_as_uint(x);
    return (u16)((u + 0x7FFF + ((u >> 16) & 1)) >> 16);
}
__device__ __forceinline__ float bf2f(u16 h) {
    return __uint_as_float(((unsigned)h) << 16);
}
__device__ __forceinline__ void f2pair(float v, u16* h, u16* l) {
    u16 hh = f2bf(v);
    *h = hh;
    *l = f2bf(v - bf2f(hh));
}

// ---------------------------------------------------------------------------
// prep_all: [0,1152) weight bf16 pairs + biases; [1152,1220) fnn1_w transpose;
// 1220 = A-uniformity check; [1221,5573) conv1d+leaky+rmsnorm (2 rows/block).
// ---------------------------------------------------------------------------
__global__ __launch_bounds__(256)
void prep_all_k(const float* __restrict__ inp_w, const float* __restrict__ D_w,
                const float* __restrict__ fc1_w, const float* __restrict__ fc2_w,
                const float* __restrict__ fc3_w, const float* __restrict__ convlin_w,
                const float* __restrict__ out_w,
                const float* __restrict__ inp_b, const float* __restrict__ D_b,
                const float* __restrict__ fc1_b, const float* __restrict__ fc2_b,
                const float* __restrict__ fc3_b,
                const float* __restrict__ W1, const float* __restrict__ A,
                const float* __restrict__ xin, const float* __restrict__ cw,
                const float* __restrict__ cb, const float* __restrict__ nw,
                u16* __restrict__ wc1h, u16* __restrict__ wc1l,
                u16* __restrict__ wc3h, u16* __restrict__ wc3l,
                u16* __restrict__ cvh,  u16* __restrict__ cvl,
                u16* __restrict__ owh,  u16* __restrict__ owl,
                float* __restrict__ bias1, float* __restrict__ bias3,
                float* __restrict__ W1T, int* __restrict__ flag,
                u16* __restrict__ XNh, u16* __restrict__ XNl)
{
    const int bx  = blockIdx.x;
    const int tid = threadIdx.x;
    __shared__ float tile[64][65];
    __shared__ float wsum[4];
    __shared__ int sflag;

    if (bx < 1152) {
        int i = bx * 256 + tid;
        if (i < 65536) {
            float v = (i < 32768) ? inp_w[i] : D_w[i - 32768];
            f2pair(v, &wc1h[i], &wc1l[i]);
        } else if (i < 196608) {
            int j = i - 65536;
            float v = (j < 65536) ? fc1_w[j] : (j < 98304 ? fc2_w[j - 65536] : fc3_w[j - 98304]);
            f2pair(v, &wc3h[j], &wc3l[j]);
        } else if (i < 262144) {
            int j = i - 196608;
            f2pair(convlin_w[j], &cvh[j], &cvl[j]);
        } else if (i < 294912) {
            int j = i - 262144;
            f2pair(out_w[j], &owh[j], &owl[j]);
        }
        if (i < 512)  bias1[i] = (i < 256) ? inp_b[i] : D_b[i - 256];
        else if (i < 1024) {
            int j = i - 512;
            bias3[j] = (j < 256) ? fc1_b[j] : (j < 384 ? fc2_b[j - 256] : fc3_b[j - 384]);
        }
    } else if (bx < 1220) {
        const int bt = bx - 1152;
        for (int p = 0; p < 16; p++) {
            int idx = tid + p * 256;
            int r = idx >> 6, c = idx & 63;
            tile[r][c] = W1[(size_t)r * 4352 + bt * 64 + c];
        }
        __syncthreads();
        for (int p = 0; p < 16; p++) {
            int idx = tid + p * 256;
            int cc = idx >> 6, rr = idx & 63;
            W1T[(size_t)(bt * 64 + cc) * 64 + rr] = tile[rr][cc];
        }
    } else if (bx == 1220) {
        if (tid == 0) sflag = 1;
        __syncthreads();
        bool ok = true;
        for (int k = 0; k < 128; k++) {
            int idx = tid + k * 256;
            ok &= (A[idx] == A[idx & ~127]);
        }
        if (!ok) sflag = 0;
        __syncthreads();
        if (tid == 0) *flag = sflag;
    } else {
        // conv1d(1->128,k=20,s=5)+leaky, RMSNorm over d=128; 2 rows per block
        const int half = tid >> 7;         // row within block
        const int c    = tid & 127;        // channel
        const int bl   = (bx - 1221) * 2 + half;
        const int b = bl / LL, l = bl % LL;
        const float* xr = xin + (size_t)b * 189 + l * 5;
        float g = cb[c];
        #pragma unroll
        for (int k = 0; k < 20; k++) g = fmaf(xr[k], cw[c * 20 + k], g);
        g = leaky_f(g);
        float s = g * g;
        #pragma unroll
        for (int m = 32; m >= 1; m >>= 1) s += __shfl_xor(s, m);
        if ((tid & 63) == 0) wsum[tid >> 6] = s;
        __syncthreads();
        float mean = (wsum[half * 2] + wsum[half * 2 + 1]) * (1.f / 128.f);
        float inv = 1.f / sqrtf(mean + 1e-5f);
        float v = g * inv * nw[c];
        f2pair(v, &XNh[(size_t)bl * DD + c], &XNl[(size_t)bl * DD + c]);
    }
}

// ---------------------------------------------------------------------------
// Split-bf16 MFMA GEMM.  Block 128 x BN, 4 waves (wm: 64-row half, wn:
// BN/2-col half), wave tile 64 x BN/2 of 16x16, K-step 32; 3 MFMA per pair.
// EPI: 0 fp32 out; 1 fp32+softplus cols<256; 2 bf16-pair out;
//      3 fp32+softplus cols<256 + bf16-pair B/C emit into BC strided rows
//        (row r base = BC + r*1024: [Bh 128|Bl 128|Ch 128|Cl 128] u16).
// ---------------------------------------------------------------------------
template <int K, int BN, int EPI>
__global__ __launch_bounds__(256)
void mgemm_k(const u16* __restrict__ Ah, const u16* __restrict__ Al,
             const u16* __restrict__ Wh, const u16* __restrict__ Wl,
             const float* __restrict__ bias,
             float* __restrict__ Y, int ldy,
             u16* __restrict__ Yh, u16* __restrict__ Yl,
             u16* __restrict__ BC)
{
    constexpr int JT = BN / 32;          // col 16-tiles per wave
    const int tid  = threadIdx.x;
    const int r0   = blockIdx.x * 128;
    const int c0   = blockIdx.y * BN;
    const int wave = tid >> 6;
    const int lane = tid & 63;
    const int wm   = wave & 1;
    const int wn   = wave >> 1;
    const int l15  = lane & 15;
    const int lq   = lane >> 4;

    __shared__ u16 sAh[128][40];
    __shared__ u16 sAl[128][40];
    __shared__ u16 sBh[BN][40];
    __shared__ u16 sBl[BN][40];

    f32x4 acc[4][JT];
    #pragma unroll
    for (int i = 0; i < 4; i++)
        #pragma unroll
        for (int j = 0; j < JT; j++) acc[i][j] = (f32x4){0.f, 0.f, 0.f, 0.f};

    const int a_row = tid >> 1;
    const int a_kb  = (tid & 1) * 16;
    const int b_row = (BN == 128) ? (tid >> 1) : (tid >> 2);
    const int b_ko  = (BN == 128) ? ((tid & 1) * 16) : ((tid & 3) * 8);

    for (int k0 = 0; k0 < K; k0 += 32) {
        const u16* ga = Ah + (size_t)(r0 + a_row) * K + k0 + a_kb;
        const u16* gl = Al + (size_t)(r0 + a_row) * K + k0 + a_kb;
        short8 vh0 = *(const short8*)(ga);
        short8 vh1 = *(const short8*)(ga + 8);
        short8 vl0 = *(const short8*)(gl);
        short8 vl1 = *(const short8*)(gl + 8);
        const u16* gb = Wh + (size_t)(c0 + b_row) * K + k0 + b_ko;
        const u16* gc = Wl + (size_t)(c0 + b_row) * K + k0 + b_ko;
        short8 wb0 = *(const short8*)(gb);
        short8 wc0 = *(const short8*)(gc);
        short8 wb1, wc1;
        if (BN == 128) {
            wb1 = *(const short8*)(gb + 8);
            wc1 = *(const short8*)(gc + 8);
        }

        *(short8*)&sAh[a_row][a_kb]     = vh0;
        *(short8*)&sAh[a_row][a_kb + 8] = vh1;
        *(short8*)&sAl[a_row][a_kb]     = vl0;
        *(short8*)&sAl[a_row][a_kb + 8] = vl1;
        *(short8*)&sBh[b_row][b_ko] = wb0;
        *(short8*)&sBl[b_row][b_ko] = wc0;
        if (BN == 128) {
            *(short8*)&sBh[b_row][b_ko + 8] = wb1;
            *(short8*)&sBl[b_row][b_ko + 8] = wc1;
        }
        __syncthreads();

        short8 fah[4], fal[4], fbh[JT], fbl[JT];
        #pragma unroll
        for (int i = 0; i < 4; i++) {
            fah[i] = *(const short8*)&sAh[wm * 64 + i * 16 + l15][lq * 8];
            fal[i] = *(const short8*)&sAl[wm * 64 + i * 16 + l15][lq * 8];
        }
        #pragma unroll
        for (int j = 0; j < JT; j++) {
            fbh[j] = *(const short8*)&sBh[wn * (BN / 2) + j * 16 + l15][lq * 8];
            fbl[j] = *(const short8*)&sBl[wn * (BN / 2) + j * 16 + l15][lq * 8];
        }
        #pragma unroll
        for (int i = 0; i < 4; i++)
            #pragma unroll
            for (int j = 0; j < JT; j++) {
                acc[i][j] = __builtin_amdgcn_mfma_f32_16x16x32_bf16(fah[i], fbh[j], acc[i][j], 0, 0, 0);
                acc[i][j] = __builtin_amdgcn_mfma_f32_16x16x32_bf16(fah[i], fbl[j], acc[i][j], 0, 0, 0);
                acc[i][j] = __builtin_amdgcn_mfma_f32_16x16x32_bf16(fal[i], fbh[j], acc[i][j], 0, 0, 0);
            }
        __syncthreads();
    }

    #pragma unroll
    for (int i = 0; i < 4; i++) {
        int gr = r0 + wm * 64 + i * 16 + lq * 4;
        #pragma unroll
        for (int j = 0; j < JT; j++) {
            int gc = c0 + wn * (BN / 2) + j * 16 + l15;
            float bb = bias[gc];
            #pragma unroll
            for (int r = 0; r < 4; r++) {
                float v = acc[i][j][r] + bb;
                if (EPI == 1 || EPI == 3) { if (gc < 256) v = softplus_f(v); }
                if (EPI == 2) {
                    u16 hh, ll;
                    f2pair(v, &hh, &ll);
                    Yh[(size_t)(gr + r) * ldy + gc] = hh;
                    Yl[(size_t)(gr + r) * ldy + gc] = ll;
                } else {
                    Y[(size_t)(gr + r) * ldy + gc] = v;
                    if (EPI == 3 && gc >= 256) {
                        u16 hh, ll;
                        f2pair(v, &hh, &ll);
                        u16* rb = BC + (size_t)(gr + r) * 1024
                                     + ((gc < 384) ? 0 : 256) + (gc & 127);
                        rb[0]   = hh;
                        rb[128] = ll;
                    }
                }
            }
        }
    }
}

// ---------------------------------------------------------------------------
// seqconv: Conv1d over L as channels + bias + silu; emits bf16 hi/lo pair.
// ---------------------------------------------------------------------------
__global__ __launch_bounds__(256)
void seqconv_k(const float* __restrict__ XP, int ldxp,
               const float* __restrict__ w, const float* __restrict__ bias,
               u16* __restrict__ XCh, u16* __restrict__ XCl)
{
    const int b   = blockIdx.x;
    const int tid = threadIdx.x;
    const int tx  = tid & 63;
    const int ty  = tid >> 6;
    const int j0  = tx * 4;

    __shared__ float sx[LL][264];
    __shared__ float sw[LL][112];

    for (int idx = tid; idx < LL * 256; idx += 256) {
        int li = idx >> 8, jj = idx & 255;
        sx[li][jj + 1] = XP[(size_t)(b * LL + li) * ldxp + jj];
    }
    if (tid < LL) { sx[tid][0] = 0.f; sx[tid][257] = 0.f; }
    for (int idx = tid; idx < LL * LL * 3; idx += 256) {
        int lo = idx / 102;
        int rem = idx - lo * 102;
        int li = rem / 3;
        int k  = rem - li * 3;
        sw[li][lo * 3 + k] = w[idx];
    }
    __syncthreads();

    const int base = ty * 9 - (ty == 3 ? 1 : 0);
    const int cnt  = (ty < 2) ? 9 : 8;

    float acc[9][4];
    #pragma unroll
    for (int i = 0; i < 9; i++)
        #pragma unroll
        for (int jj = 0; jj < 4; jj++) acc[i][jj] = 0.f;

    for (int li = 0; li < LL; li++) {
        float4 xa = *(const float4*)&sx[li][j0];
        float2 xb = *(const float2*)&sx[li][j0 + 4];
        float xv[6] = {xa.x, xa.y, xa.z, xa.w, xb.x, xb.y};
        const float* swr = &sw[li][0];
        #pragma unroll
        for (int i = 0; i < 9; i++) {
            if (i < cnt) {
                int lo3 = (base + i) * 3;
                float w0 = swr[lo3 + 0];
                float w1 = swr[lo3 + 1];
                float w2 = swr[lo3 + 2];
                #pragma unroll
                for (int jj = 0; jj < 4; jj++) {
                    acc[i][jj] = fmaf(w0, xv[jj],     acc[i][jj]);
                    acc[i][jj] = fmaf(w1, xv[jj + 1], acc[i][jj]);
                    acc[i][jj] = fmaf(w2, xv[jj + 2], acc[i][jj]);
                }
            }
        }
    }

    #pragma unroll
    for (int i = 0; i < 9; i++) {
        if (i < cnt) {
            int lo = base + i;
            float bb = bias[lo];
            ushort4 oh, ol;
            float v0 = silu_f(acc[i][0] + bb);
            float v1 = silu_f(acc[i][1] + bb);
            float v2 = silu_f(acc[i][2] + bb);
            float v3 = silu_f(acc[i][3] + bb);
            f2pair(v0, &oh.x, &ol.x);
            f2pair(v1, &oh.y, &ol.y);
            f2pair(v2, &oh.z, &ol.z);
            f2pair(v3, &oh.w, &ol.w);
            size_t o = (size_t)(b * LL + lo) * DI + j0;
            *(ushort4*)&XCh[o] = oh;
            *(ushort4*)&XCl[o] = ol;
        }
    }
}

// ---------------------------------------------------------------------------
// ssd_tail<Q>: triangular contraction for l = Q, Q+4, ... (static unroll so
// u[]/eS[] stay in registers), + fused silu gate, bf16-pair store.
// ---------------------------------------------------------------------------
template <int Q>
__device__ __forceinline__ void ssd_tail(const float (*Msh)[49],
                                         const float (&u)[LL], const float (&eS)[LL],
                                         const float* __restrict__ pG,
                                         u16* __restrict__ pGh, u16* __restrict__ pGl)
{
    #pragma unroll
    for (int l = Q; l < LL; l += 4) {
        float acc = 0.f;
        #pragma unroll
        for (int t = 0; t <= l; t++) acc = fmaf(Msh[l][t], u[t], acc);
        float xs = eS[l] * acc;
        float g = silu_f(xs) * silu_f(pG[l * 512]);
        u16 hh, ll2;
        f2pair(g, &hh, &ll2);
        pGh[l * 256] = hh;
        pGl[l * 256] = ll2;
    }
}

// ---------------------------------------------------------------------------
// Merged scan, grid (4, NB).  Uniform-A path (flag=1): SSD closed form —
// M = C.B^T via MFMA on bf16 pairs; block handles d in [bx*64, bx*64+64),
// thread = (d = bx*64 + lane&63, quarter q = tid>>6); quarters split output
// l's (l = q mod 4).  General-A path (flag=0): sequential recurrence,
// d0 = bx*64, identical to round-5 fallback.
// ---------------------------------------------------------------------------
__global__ __launch_bounds__(256)
void scan_k(const int* __restrict__ flag,
            const float* __restrict__ dBC,   // [8704,512] delta|B|C fp32
            const u16* __restrict__ BC,      // strided bf16 pairs, row*1024
            const u16* __restrict__ Xh, const u16* __restrict__ Xl,
            const float* __restrict__ A,
            const float* __restrict__ DG,    // buf1, dgate at cols 256+
            u16* __restrict__ Gh, u16* __restrict__ Gl)
{
    const int bx  = blockIdx.x;
    const int b   = blockIdx.y;
    const int tid = threadIdx.x;

    __shared__ u16 sBh[48][136], sBl[48][136];
    __shared__ u16 sCh[48][136], sCl[48][136];
    __shared__ float sM[48][49];

    if (*flag != 0) {
        const int wave = tid >> 6;
        const int lane = tid & 63;
        const int l15  = lane & 15;
        const int lq   = lane >> 4;

        // ---- stage bf16 B/C pairs ----
        const u16* base = BC + (size_t)b * LL * 1024;
        for (int idx = tid; idx < LL * 16; idx += 256) {
            int l = idx >> 4, c = (idx & 15) << 3;
            const u16* row = base + l * 1024;
            *(short8*)&sBh[l][c] = *(const short8*)&row[c];
            *(short8*)&sBl[l][c] = *(const short8*)&row[128 + c];
            *(short8*)&sCh[l][c] = *(const short8*)&row[256 + c];
            *(short8*)&sCl[l][c] = *(const short8*)&row[384 + c];
        }
        __syncthreads();

        // ---- M = C.B^T via MFMA (3x3 16-tiles, K=128 in 4 steps) ----
        for (int tt = wave; tt < 9; tt += 4) {
            int ti = tt / 3, tj = tt - ti * 3;
            f32x4 acc = (f32x4){0.f, 0.f, 0.f, 0.f};
            #pragma unroll
            for (int ks = 0; ks < 4; ks++) {
                short8 ch = *(const short8*)&sCh[ti * 16 + l15][ks * 32 + lq * 8];
                short8 cl = *(const short8*)&sCl[ti * 16 + l15][ks * 32 + lq * 8];
                short8 bh = *(const short8*)&sBh[tj * 16 + l15][ks * 32 + lq * 8];
                short8 bl = *(const short8*)&sBl[tj * 16 + l15][ks * 32 + lq * 8];
                acc = __builtin_amdgcn_mfma_f32_16x16x32_bf16(ch, bh, acc, 0, 0, 0);
                acc = __builtin_amdgcn_mfma_f32_16x16x32_bf16(ch, bl, acc, 0, 0, 0);
                acc = __builtin_amdgcn_mfma_f32_16x16x32_bf16(cl, bh, acc, 0, 0, 0);
            }
            #pragma unroll
            for (int r = 0; r < 4; r++)
                sM[ti * 16 + lq * 4 + r][tj * 16 + l15] = acc[r];
        }
        __syncthreads();

        // ---- per-d cumsum + u (quarters redundant), split-l tail ----
        const int d = (bx << 6) + lane;
        const int q = wave;
        const float a_d = A[(size_t)d * NN];
        const float* pDel = dBC + (size_t)b * LL * 512 + d;
        const u16* pXh = Xh + (size_t)b * LL * 256 + d;
        const u16* pXl = Xl + (size_t)b * LL * 256 + d;

        float u[LL], eS[LL];
        float S = 0.f;
        #pragma unroll
        for (int l = 0; l < LL; l++) {
            float dl = pDel[l * 512];
            S = fmaf(dl, a_d, S);
            eS[l] = __expf(S);
            float xv = bf2f(pXh[l * 256]) + bf2f(pXl[l * 256]);
            u[l] = __expf(-S) * dl * xv;
        }

        const float* pG = DG + (size_t)b * LL * 512 + 256 + d;
        u16* pGh = Gh + (size_t)b * LL * 256 + d;
        u16* pGl = Gl + (size_t)b * LL * 256 + d;
        switch (q) {
            case 0: ssd_tail<0>(sM, u, eS, pG, pGh, pGl); break;
            case 1: ssd_tail<1>(sM, u, eS, pG, pGh, pGl); break;
            case 2: ssd_tail<2>(sM, u, eS, pG, pGh, pGl); break;
            default: ssd_tail<3>(sM, u, eS, pG, pGh, pGl); break;
        }
        return;
    }

    // ---------------- general-A sequential fallback ----------------
    const int d0 = bx * 64;
    const int sub = tid & 15;
    const int pg  = tid >> 4;
    const int dbase = d0 + pg * 4;
    const int nA = sub * 4;

    float a[4][8], h[4][8];
    #pragma unroll
    for (int dd = 0; dd < 4; dd++) {
        const float* Ar = A + (size_t)(dbase + dd) * NN;
        float4 q0 = *(const float4*)(Ar + nA);
        float4 q1 = *(const float4*)(Ar + 64 + nA);
        a[dd][0]=q0.x; a[dd][1]=q0.y; a[dd][2]=q0.z; a[dd][3]=q0.w;
        a[dd][4]=q1.x; a[dd][5]=q1.y; a[dd][6]=q1.z; a[dd][7]=q1.w;
        #pragma unroll
        for (int j = 0; j < 8; j++) h[dd][j] = 0.f;
    }

    const float* pD  = dBC + (size_t)b * LL * 512 + dbase;
    const float* pBC = dBC + (size_t)b * LL * 512 + 256 + nA;
    const u16*  pXh = Xh  + (size_t)b * LL * 256 + dbase;
    const u16*  pXl = Xl  + (size_t)b * LL * 256 + dbase;
    const float* pG  = DG  + (size_t)b * LL * 512 + 256 + dbase;
    u16* pGh = Gh + (size_t)b * LL * 256 + dbase;
    u16* pGl = Gl + (size_t)b * LL * 256 + dbase;

    for (int l = 0; l < LL; l++) {
        float4  cD  = *(const float4*)(pD);
        ushort4 cXh = *(const ushort4*)(pXh);
        ushort4 cXl = *(const ushort4*)(pXl);
        float4 cB0 = *(const float4*)(pBC);
        float4 cB1 = *(const float4*)(pBC + 64);
        float4 cC0 = *(const float4*)(pBC + 128);
        float4 cC1 = *(const float4*)(pBC + 192);
        pD += 512; pBC += 512; pXh += 256; pXl += 256;

        float xv[4] = { bf2f(cXh.x) + bf2f(cXl.x), bf2f(cXh.y) + bf2f(cXl.y),
                        bf2f(cXh.z) + bf2f(cXl.z), bf2f(cXh.w) + bf2f(cXl.w) };
        float dl[4] = {cD.x, cD.y, cD.z, cD.w};
        float dx[4] = {cD.x * xv[0], cD.y * xv[1], cD.z * xv[2], cD.w * xv[3]};
        float bv[8] = {cB0.x,cB0.y,cB0.z,cB0.w,cB1.x,cB1.y,cB1.z,cB1.w};
        float cv[8] = {cC0.x,cC0.y,cC0.z,cC0.w,cC1.x,cC1.y,cC1.z,cC1.w};

        float accd[4] = {0.f, 0.f, 0.f, 0.f};
        #pragma unroll
        for (int dd = 0; dd < 4; dd++)
            #pragma unroll
            for (int j = 0; j < 8; j++) {
                float dA = __expf(dl[dd] * a[dd][j]);
                h[dd][j] = fmaf(dA, h[dd][j], dx[dd] * bv[j]);
                accd[dd] = fmaf(cv[j], h[dd][j], accd[dd]);
            }
        #pragma unroll
        for (int dd = 0; dd < 4; dd++) {
            float v = accd[dd];
            v += __shfl_xor(v, 1);
            v += __shfl_xor(v, 2);
            v += __shfl_xor(v, 4);
            v += __shfl_xor(v, 8);
            accd[dd] = v;
        }
        if (sub == 0) {
            float4 dg = *(const float4*)(pG);
            ushort4 oh, ol;
            float g0 = silu_f(accd[0]) * silu_f(dg.x);
            float g1 = silu_f(accd[1]) * silu_f(dg.y);
            float g2 = silu_f(accd[2]) * silu_f(dg.z);
            float g3 = silu_f(accd[3]) * silu_f(dg.w);
            f2pair(g0, &oh.x, &ol.x);
            f2pair(g1, &oh.y, &ol.y);
            f2pair(g2, &oh.z, &ol.z);
            f2pair(g3, &oh.w, &ol.w);
            *(ushort4*)pGh = oh;
            *(ushort4*)pGl = ol;
        }
        pG += 512; pGh += 256; pGl += 256;
    }
}

// ---------------------------------------------------------------------------
// FNN stage 1: split-K partials (deterministic).
// ---------------------------------------------------------------------------
__global__ __launch_bounds__(256)
void fnn1_k(const float* __restrict__ F, const float* __restrict__ W1T,
            float* __restrict__ partials)
{
    const int btile = blockIdx.x;
    const int kc    = blockIdx.y;
    const int tid   = threadIdx.x;
    __shared__ float sf[16][260];
    for (int i = tid; i < 16 * 256; i += 256) {
        int r = i >> 8, c = i & 255;
        sf[r][c] = F[(size_t)(btile * 16 + r) * 4352 + kc * 256 + c];
    }
    __syncthreads();

    const int o  = tid & 63;
    const int bq = tid >> 6;
    const float* w = W1T + (size_t)(kc * 256) * 64 + o;
    float acc[4] = {0.f, 0.f, 0.f, 0.f};
    for (int k = 0; k < 256; k += 4) {
        float w0 = w[(size_t)(k + 0) * 64];
        float w1 = w[(size_t)(k + 1) * 64];
        float w2 = w[(size_t)(k + 2) * 64];
        float w3 = w[(size_t)(k + 3) * 64];
        #pragma unroll
        for (int bj = 0; bj < 4; bj++) {
            float4 f4 = *(const float4*)&sf[bq * 4 + bj][k];
            acc[bj] = fmaf(w0, f4.x, acc[bj]);
            acc[bj] = fmaf(w1, f4.y, acc[bj]);
            acc[bj] = fmaf(w2, f4.z, acc[bj]);
            acc[bj] = fmaf(w3, f4.w, acc[bj]);
        }
    }
    #pragma unroll
    for (int bj = 0; bj < 4; bj++)
        partials[(size_t)kc * 16384 + (btile * 16 + bq * 4 + bj) * 64 + o] = acc[bj];
}

// ---------------------------------------------------------------------------
// FNN stage 2: reduce partials, leaky, then @fnn2_w.T + b2 -> out[b][32].
// ---------------------------------------------------------------------------
__global__ __launch_bounds__(64)
void fnn2_k(const float* __restrict__ partials,
            const float* __restrict__ B1,
            const float* __restrict__ W2, const float* __restrict__ B2,
            float* __restrict__ out)
{
    int b = blockIdx.x;
    int t = threadIdx.x;
    __shared__ float s1[64];
    float acc = B1[t];
    #pragma unroll
    for (int kc = 0; kc < 17; kc++)
        acc += partials[(size_t)kc * 16384 + b * 64 + t];
    s1[t] = leaky_f(acc);
    __syncthreads();

    if (t < 32) {
        float acc2 = B2[t];
        const float* w2 = W2 + t * 64;
        #pragma unroll
        for (int j = 0; j < 64; j++) acc2 = fmaf(s1[j], w2[j], acc2);
        out[(size_t)b * 32 + t] = acc2;
    }
}

// ---------------------------------------------------------------------------
extern "C" void kernel_launch(void* const* d_in, const int* in_sizes, int n_in,
                              void* d_out, int out_size, void* d_ws, size_t ws_size,
                              hipStream_t stream)
{
    const float* x        = (const float*)d_in[0];
    const float* conv_w   = (const float*)d_in[1];
    const float* conv_b   = (const float*)d_in[2];
    const float* norm_w   = (const float*)d_in[3];
    const float* inp_w    = (const float*)d_in[4];
    const float* inp_b    = (const float*)d_in[5];
    const float* seqconv_w= (const float*)d_in[6];
    const float* seqconv_b= (const float*)d_in[7];
    const float* convlin_w= (const float*)d_in[8];
    const float* convlin_b= (const float*)d_in[9];
    const float* fc1_w    = (const float*)d_in[10];
    const float* fc1_b    = (const float*)d_in[11];
    const float* fc2_w    = (const float*)d_in[12];
    const float* fc2_b    = (const float*)d_in[13];
    const float* fc3_w    = (const float*)d_in[14];
    const float* fc3_b    = (const float*)d_in[15];
    const float* A        = (const float*)d_in[16];
    const float* D_w      = (const float*)d_in[17];
    const float* D_b      = (const float*)d_in[18];
    const float* out_w    = (const float*)d_in[19];
    const float* out_b    = (const float*)d_in[20];
    const float* fnn1_w   = (const float*)d_in[21];
    const float* fnn1_b   = (const float*)d_in[22];
    const float* fnn2_w   = (const float*)d_in[23];
    const float* fnn2_b   = (const float*)d_in[24];

    // ---- workspace layout (bytes) ----
    char* W = (char*)d_ws;
    float* buf1  = (float*)(W + 0);           // [8704,512] fp32  xp|dgate;
                                              // xp half reused for bf16 B/C pairs
    float* buf3  = (float*)(W + 17825792);    // [8704,512] fp32  delta|B|C ; partials later
    u16*   xnh   = (u16*)  (W + 35651584);    // [8704,128]
    u16*   xnl   = (u16*)  (W + 37879808);
    u16*   xc2h  = (u16*)  (W + 35651584);    // [8704,256] (xn dead)
    float* fout  = (float*)(W + 35651584);    // [8704,128] fp32 (later)
    u16*   xc2l  = (u16*)  (W + 40108032);    // [8704,256]
    u16*   xch   = (u16*)  (W + 44564480);    // [8704,256] ; gateh later
    u16*   xcl   = (u16*)  (W + 49020928);    // [8704,256] ; gatel later
    float* w1t   = (float*)(W + 53477376);    // [4352,64]
    u16*   wc1h  = (u16*)  (W + 54591488);
    u16*   wc1l  = (u16*)  (W + 54722560);
    u16*   wc3h  = (u16*)  (W + 54853632);
    u16*   wc3l  = (u16*)  (W + 55115776);
    u16*   cvh   = (u16*)  (W + 55377920);
    u16*   cvl   = (u16*)  (W + 55508992);
    u16*   owh   = (u16*)  (W + 55640064);
    u16*   owl   = (u16*)  (W + 55705600);
    float* bias1 = (float*)(W + 55771136);
    float* bias3 = (float*)(W + 55773184);
    int*   uflag = (int*)  (W + 55775232);
    u16* gateh = xch;
    u16* gatel = xcl;
    u16* bcpair = (u16*)buf1;                 // xp half of buf1 (dead after seqconv)
    float* partials = buf3;

    // prep (weights, transpose, A-check) + conv/rmsnorm fused
    prep_all_k<<<5573, 256, 0, stream>>>(inp_w, D_w, fc1_w, fc2_w, fc3_w,
                                         convlin_w, out_w,
                                         inp_b, D_b, fc1_b, fc2_b, fc3_b,
                                         fnn1_w, A, x, conv_w, conv_b, norm_w,
                                         wc1h, wc1l, wc3h, wc3l, cvh, cvl,
                                         owh, owl, bias1, bias3, w1t, uflag,
                                         xnh, xnl);

    // buf1 = xn @ [inp_w;D_w].T + [inp_b|D_b]          (fp32 out)
    mgemm_k<128, 64, 0><<<dim3(MM / 128, 8), 256, 0, stream>>>(
        xnh, xnl, wc1h, wc1l, bias1, buf1, 512, nullptr, nullptr, nullptr);

    seqconv_k<<<NB, 256, 0, stream>>>(buf1, 512, seqconv_w, seqconv_b, xch, xcl);

    // xc2 = xc @ convlin_w.T + convlin_b               (bf16-pair out)
    mgemm_k<256, 64, 2><<<dim3(MM / 128, 4), 256, 0, stream>>>(
        xch, xcl, cvh, cvl, convlin_b, nullptr, 256, xc2h, xc2l, nullptr);

    // buf3 = xc2 @ [fc1;fc2;fc3].T + bias3, softplus on delta cols,
    // B/C also emitted as bf16 pairs into buf1's xp half
    mgemm_k<256, 64, 3><<<dim3(MM / 128, 8), 256, 0, stream>>>(
        xc2h, xc2l, wc3h, wc3l, bias3, buf3, 512, nullptr, nullptr, bcpair);

    // merged scan: SSD (uniform A, MFMA M) or sequential fallback
    scan_k<<<dim3(4, NB), 256, 0, stream>>>(uflag, buf3, bcpair, xc2h, xc2l,
                                            A, buf1, gateh, gatel);

    // fout = gate @ out_w.T + out_b                    (fp32 out)
    mgemm_k<256, 64, 0><<<dim3(MM / 128, 2), 256, 0, stream>>>(
        gateh, gatel, owh, owl, out_b, fout, 128, nullptr, nullptr, nullptr);

    fnn1_k<<<dim3(16, 17), 256, 0, stream>>>(fout, w1t, partials);
    fnn2_k<<<NB, 64, 0, stream>>>(partials, fnn1_b, fnn2_w, fnn2_b,
                                  (float*)d_out);
}